// Round 15
// baseline (299.330 us; speedup 1.0000x reference)
//
#include <hip/hip_runtime.h>
#include <math.h>

// ---------------------------------------------------------------------------
// EdgeCorrGNN: 4x GCNConv(+relu) + Linear(256,1).
// R15: R14 base; N>=128 GEMMs move to 128x128 tile (2x2 waves of 64x64,
// 0.5 ds_reads/MFMA, 2x A-fragment reuse). Gathers/preproc unchanged.
// ---------------------------------------------------------------------------

typedef _Float16 half8 __attribute__((ext_vector_type(8)));
typedef _Float16 half4_t __attribute__((ext_vector_type(4)));
typedef float f32x4 __attribute__((ext_vector_type(4)));

#define SCAN_CHUNK 2048           // nodes per scan block (256 thr x 8)
#define DEG_SCALE 67108864.0f     // 2^26 fixed-point scale for weighted degree
#define DEG_MASK ((1ULL << 42) - 1)
#define NW 114688                 // total W1..W4 elements

// fused: convert W1..W4 to fp16 AND init packed degree array.
__global__ __launch_bounds__(256) void k_cvtw_init(const float* __restrict__ W1,
                                                   const float* __restrict__ W2,
                                                   const float* __restrict__ W3,
                                                   const float* __restrict__ W4,
                                                   _Float16* __restrict__ out,
                                                   unsigned long long* __restrict__ packed,
                                                   int n) {
    int i = blockIdx.x * 256 + threadIdx.x;
    if (i < NW) {
        const float* src; int off;
        if (i < 8192)       { src = W1; off = 0; }
        else if (i < 16384) { src = W2; off = 8192; }
        else if (i < 49152) { src = W3; off = 16384; }
        else                { src = W4; off = 49152; }
        out[i] = (_Float16)src[i - off];
    } else {
        int j = i - NW;
        if (j < n) packed[j] = (1ULL << 26);   // deg=1.0 (self-loop), cnt=0
    }
}

// one u64 atomic per edge; returned old count = slot within the dst row.
__global__ __launch_bounds__(256) void k_count_slot(const int* __restrict__ dst,
                                                    const float* __restrict__ w,
                                                    unsigned long long* __restrict__ packed,
                                                    int* __restrict__ slot, int e) {
    int i = blockIdx.x * 256 + threadIdx.x;
    if (i < e) {
        unsigned long long wf = (unsigned long long)(w[i] * DEG_SCALE + 0.5f);
        unsigned long long old = atomicAdd(&packed[dst[i]], (1ULL << 42) | wf);
        slot[i] = (int)(old >> 42);
    }
}

// fused: unpack packed -> dinv + per-chunk local exclusive scan of counts.
__global__ __launch_bounds__(256) void k_dinv_scan(const unsigned long long* __restrict__ packed,
                                                   float* __restrict__ dinv,
                                                   int* __restrict__ row_ptr,
                                                   int* __restrict__ blocksum, int n) {
    __shared__ int sp[256];
    int tid = threadIdx.x;
    int base = blockIdx.x * SCAN_CHUNK + tid * 8;
    int c[8] = {0, 0, 0, 0, 0, 0, 0, 0};
    if (base < n) {
#pragma unroll
        for (int j = 0; j < 8; ++j) {
            unsigned long long p = packed[base + j];
            float d = (float)((double)(p & DEG_MASK) * (1.0 / 67108864.0));
            dinv[base + j] = d > 0.0f ? rsqrtf(d) : 0.0f;
            c[j] = (int)(p >> 42);
        }
    }
    int s = c[0] + c[1] + c[2] + c[3] + c[4] + c[5] + c[6] + c[7];
    sp[tid] = s;
    __syncthreads();
    for (int d = 1; d < 256; d <<= 1) {
        int t = (tid >= d) ? sp[tid - d] : 0;
        __syncthreads();
        sp[tid] += t;
        __syncthreads();
    }
    int off = (tid == 0) ? 0 : sp[tid - 1];
    if (base < n) {
        int o[8];
        int run = off;
#pragma unroll
        for (int j = 0; j < 8; ++j) { o[j] = run; run += c[j]; }
        *(int4*)(row_ptr + base)     = make_int4(o[0], o[1], o[2], o[3]);
        *(int4*)(row_ptr + base + 4) = make_int4(o[4], o[5], o[6], o[7]);
    }
    if (tid == 255) blocksum[blockIdx.x] = sp[255];
}

// fused: wave 0 prefix-scans the (<=64) block sums; all blocks add offset.
__global__ __launch_bounds__(256) void k_scan_add(int* __restrict__ row_ptr,
                                                  const int* __restrict__ blocksum,
                                                  int n, int total, int nb) {
    __shared__ int bo[64];
    int tid = threadIdx.x;
    if (tid < 64) {
        int c = (tid < nb) ? blocksum[tid] : 0;
        int v = c;
        for (int d = 1; d < 64; d <<= 1) {
            int t = __shfl_up(v, d);
            if (tid >= d) v += t;
        }
        bo[tid] = v - c;
    }
    __syncthreads();
    int base = blockIdx.x * SCAN_CHUNK + tid * 8;
    if (base < n) {
        int off = bo[blockIdx.x];
        int4 a = *(const int4*)(row_ptr + base);
        int4 b = *(const int4*)(row_ptr + base + 4);
        a.x += off; a.y += off; a.z += off; a.w += off;
        b.x += off; b.y += off; b.z += off; b.w += off;
        *(int4*)(row_ptr + base)     = a;
        *(int4*)(row_ptr + base + 4) = b;
    }
    if (blockIdx.x == 0 && tid == 0) row_ptr[n] = total;
}

// csr[row_ptr[dst] + slot] = (src, norm) -- pure scatter, no atomics.
__global__ __launch_bounds__(256) void k_fill(const int* __restrict__ src,
                                              const int* __restrict__ dst,
                                              const float* __restrict__ w,
                                              const float* __restrict__ dinv,
                                              const int* __restrict__ row_ptr,
                                              const int* __restrict__ slot,
                                              float2* __restrict__ csr, int e) {
    int i = blockIdx.x * 256 + threadIdx.x;
    if (i < e) {
        int d = dst[i], s = src[i];
        float nv = dinv[s] * w[i] * dinv[d];
        csr[row_ptr[d] + slot[i]] = make_float2(__int_as_float(s), nv);
    }
}

// ---------------------------------------------------------------------------
// fp16-MFMA GEMM. BM=128, BK=64, 4 waves. A fp32/fp16, B fp16, C fp16.
// BN=64 : waves 4x1, 32x64/wave (2x4 frags).
// BN=128: waves 2x2, 64x64/wave (4x4 frags) -- 0.5 ds_reads/MFMA.
// XCD4 (BN=128, N=256): bid -> xcd=bid&7, cb=(bid>>3)&1, rb=xcd+8*(bid>>4).
// ---------------------------------------------------------------------------
template <bool RELU, typename TA, int BN, bool XCD4>
__global__ __launch_bounds__(256) void gemm_mfma(const TA* __restrict__ A,
                                                 const _Float16* __restrict__ B,
                                                 const float* __restrict__ bias,
                                                 _Float16* __restrict__ C,
                                                 int M, int K, int N) {
    constexpr int PK = 72;
    constexpr int MR = (BN == 64) ? 2 : 4;
    __shared__ _Float16 Asl[128 * PK];
    __shared__ _Float16 Bsl[BN * PK];

    int tid = threadIdx.x;
    int w = tid >> 6, l = tid & 63;
    int row0, col0;
    if constexpr (XCD4) {
        int bid = blockIdx.x;
        int xcd = bid & 7;
        int cb = (bid >> 3) & 1;
        int rb = xcd + 8 * (bid >> 4);
        row0 = rb * 128;
        col0 = cb * BN;
    } else {
        row0 = blockIdx.x * 128;
        col0 = blockIdx.y * BN;
    }
    int lr = l & 15, lg = l >> 4;

    int wr, wc;
    if constexpr (BN == 64) { wr = w * 32; wc = 0; }
    else { wr = (w >> 1) * 64; wc = (w & 1) * 64; }

    int srow = tid >> 1;
    int skh = (tid & 1) * 32;

    f32x4 acc[MR][4] = {};

    for (int k0 = 0; k0 < K; k0 += 64) {
        // --- stage A, 32 elems/thread ---
        const TA* ap = A + (size_t)(row0 + srow) * K + k0 + skh;
        bool aok = (row0 + srow) < M;
#pragma unroll
        for (int i = 0; i < 4; ++i) {
            half8 h;
            if constexpr (sizeof(TA) == 4) {
                float4 v0 = aok ? *(const float4*)((const float*)ap + i * 8 + 0)
                                : make_float4(0.f, 0.f, 0.f, 0.f);
                float4 v1 = aok ? *(const float4*)((const float*)ap + i * 8 + 4)
                                : make_float4(0.f, 0.f, 0.f, 0.f);
                h[0] = (_Float16)v0.x; h[1] = (_Float16)v0.y;
                h[2] = (_Float16)v0.z; h[3] = (_Float16)v0.w;
                h[4] = (_Float16)v1.x; h[5] = (_Float16)v1.y;
                h[6] = (_Float16)v1.z; h[7] = (_Float16)v1.w;
            } else {
                h = aok ? *(const half8*)((const _Float16*)ap + i * 8)
                        : half8{0, 0, 0, 0, 0, 0, 0, 0};
            }
            *(half8*)&Asl[srow * PK + skh + i * 8] = h;
        }
        // --- stage B transposed ([n][k]), fp16 source ---
        if constexpr (BN == 64) {
            int bk = tid >> 4;          // 0..15
            int bn = (tid & 15) * 4;    // 0..60
#pragma unroll
            for (int r = 0; r < 4; ++r) {
                int kk = bk + r * 16;
                half4_t wv = *(const half4_t*)(B + (size_t)(k0 + kk) * N + col0 + bn);
                Bsl[(bn + 0) * PK + kk] = wv[0];
                Bsl[(bn + 1) * PK + kk] = wv[1];
                Bsl[(bn + 2) * PK + kk] = wv[2];
                Bsl[(bn + 3) * PK + kk] = wv[3];
            }
        } else {
            int bk = tid >> 5;          // 0..7
            int bn = (tid & 31) * 4;    // 0..124
#pragma unroll
            for (int r = 0; r < 8; ++r) {
                int kk = bk + r * 8;
                half4_t wv = *(const half4_t*)(B + (size_t)(k0 + kk) * N + col0 + bn);
                Bsl[(bn + 0) * PK + kk] = wv[0];
                Bsl[(bn + 1) * PK + kk] = wv[1];
                Bsl[(bn + 2) * PK + kk] = wv[2];
                Bsl[(bn + 3) * PK + kk] = wv[3];
            }
        }
        __syncthreads();

#pragma unroll
        for (int kr = 0; kr < 2; ++kr) {
            half8 af[MR], bf[4];
#pragma unroll
            for (int m = 0; m < MR; ++m)
                af[m] = *(half8*)&Asl[(wr + m * 16 + lr) * PK + kr * 32 + lg * 8];
#pragma unroll
            for (int n = 0; n < 4; ++n)
                bf[n] = *(half8*)&Bsl[(wc + n * 16 + lr) * PK + kr * 32 + lg * 8];
#pragma unroll
            for (int m = 0; m < MR; ++m)
#pragma unroll
                for (int n = 0; n < 4; ++n)
                    acc[m][n] = __builtin_amdgcn_mfma_f32_16x16x32_f16(
                        af[m], bf[n], acc[m][n], 0, 0, 0);
        }
        __syncthreads();
    }

#pragma unroll
    for (int m = 0; m < MR; ++m) {
#pragma unroll
        for (int r = 0; r < 4; ++r) {
            int row = row0 + wr + m * 16 + lg * 4 + r;
            if (row >= M) continue;
#pragma unroll
            for (int n = 0; n < 4; ++n) {
                int col = col0 + wc + n * 16 + lr;
                float v = acc[m][n][r];
                if (RELU) v = fmaxf(v + bias[col], 0.f);
                C[(size_t)row * N + col] = (_Float16)v;
            }
        }
    }
}

// ---------------------------------------------------------------------------
// Gather v2 (R8, proven): one wave per node, half4 per lane, lane-groups,
// unroll 4. Used for fo=64 layers.
// ---------------------------------------------------------------------------
template <int FO, bool BIASRELU>
__global__ __launch_bounds__(256) void k_gather2(const int* __restrict__ row_ptr,
                                                 const float2* __restrict__ csr,
                                                 const _Float16* __restrict__ H,
                                                 const float* __restrict__ dinv,
                                                 const float* __restrict__ b,
                                                 _Float16* __restrict__ O, int n) {
    constexpr int LPE = FO / 4;
    constexpr int GRP = 64 / LPE;
    int node = blockIdx.x * 4 + (threadIdx.x >> 6);
    int lane = threadIdx.x & 63;
    if (node >= n) return;
    int grp = lane / LPE;
    int cols = (lane % LPE) * 4;

    float ax = 0.f, ay = 0.f, az = 0.f, aw = 0.f;
    int e0 = row_ptr[node], e1 = row_ptr[node + 1];

    for (int e = e0; e < e1; e += 4 * GRP) {
        float nv[4]; half4_t hv[4];
#pragma unroll
        for (int u = 0; u < 4; ++u) {
            int er = e + u * GRP + grp;
            int eg = min(er, e1 - 1);
            float2 c = csr[eg];
            hv[u] = *(const half4_t*)(H + (size_t)__float_as_int(c.x) * FO + cols);
            nv[u] = (er < e1) ? c.y : 0.f;
        }
#pragma unroll
        for (int u = 0; u < 4; ++u) {
            ax += nv[u] * (float)hv[u][0];
            ay += nv[u] * (float)hv[u][1];
            az += nv[u] * (float)hv[u][2];
            aw += nv[u] * (float)hv[u][3];
        }
    }

#pragma unroll
    for (int off = LPE; off < 64; off <<= 1) {
        ax += __shfl_down(ax, off);
        ay += __shfl_down(ay, off);
        az += __shfl_down(az, off);
        aw += __shfl_down(aw, off);
    }

    if (lane < LPE) {
        float di = dinv[node];
        float s = di * di;
        half4_t hs = *(const half4_t*)(H + (size_t)node * FO + cols);
        ax += s * (float)hs[0];
        ay += s * (float)hs[1];
        az += s * (float)hs[2];
        aw += s * (float)hs[3];
        if (BIASRELU) {
            float4 bv = *(const float4*)(b + cols);
            ax = fmaxf(ax + bv.x, 0.f);
            ay = fmaxf(ay + bv.y, 0.f);
            az = fmaxf(az + bv.z, 0.f);
            aw = fmaxf(aw + bv.w, 0.f);
        }
        half4_t o;
        o[0] = (_Float16)ax; o[1] = (_Float16)ay;
        o[2] = (_Float16)az; o[3] = (_Float16)aw;
        *(half4_t*)(O + (size_t)node * FO + cols) = o;
    }
}

// ---------------------------------------------------------------------------
// half8 gather fo=128: one wave per node; 16 lanes x 16B cover the 256B row;
// 4 edge groups, unroll 4.
// ---------------------------------------------------------------------------
__global__ __launch_bounds__(256) void k_g128_h8(const int* __restrict__ row_ptr,
                                                 const float2* __restrict__ csr,
                                                 const _Float16* __restrict__ H,
                                                 const float* __restrict__ dinv,
                                                 _Float16* __restrict__ O, int n) {
    int node = blockIdx.x * 4 + (threadIdx.x >> 6);
    int lane = threadIdx.x & 63;
    if (node >= n) return;
    int grp = lane >> 4;                 // 0..3
    unsigned cols = (lane & 15) * 8;     // 0..120

    float acc[8] = {};
    int e0 = row_ptr[node], e1 = row_ptr[node + 1];

    for (int e = e0; e < e1; e += 16) {
        float nv[4]; half8 hv[4];
#pragma unroll
        for (int u = 0; u < 4; ++u) {
            int er = e + u * 4 + grp;
            int eg = min(er, e1 - 1);
            float2 c = csr[eg];
            hv[u] = *(const half8*)(H + (unsigned)__float_as_int(c.x) * 128 + cols);
            nv[u] = (er < e1) ? c.y : 0.f;
        }
#pragma unroll
        for (int u = 0; u < 4; ++u)
#pragma unroll
            for (int j = 0; j < 8; ++j)
                acc[j] += nv[u] * (float)hv[u][j];
    }

#pragma unroll
    for (int j = 0; j < 8; ++j) {
        acc[j] += __shfl_down(acc[j], 16);
        acc[j] += __shfl_down(acc[j], 32);
    }

    if (lane < 16) {
        float di = dinv[node];
        float sc = di * di;
        half8 hs = *(const half8*)(H + (unsigned)node * 128 + cols);
        half8 o;
#pragma unroll
        for (int j = 0; j < 8; ++j)
            o[j] = (_Float16)(acc[j] + sc * (float)hs[j]);
        *(half8*)(O + (unsigned)node * 128 + cols) = o;
    }
}

// ---------------------------------------------------------------------------
// half8 fused final gather (fo=256) + bias + relu + Linear(256,1).
// One wave per node; 32 lanes x 16B cover the 512B row; 2 edge groups,
// unroll 4.
// ---------------------------------------------------------------------------
__global__ __launch_bounds__(256) void k_gfinal_h8(const int* __restrict__ row_ptr,
                                                   const float2* __restrict__ csr,
                                                   const _Float16* __restrict__ H,
                                                   const float* __restrict__ dinv,
                                                   const float* __restrict__ b4,
                                                   const float* __restrict__ Wf,
                                                   const float* __restrict__ bf,
                                                   float* __restrict__ out, int n) {
    int node = blockIdx.x * 4 + (threadIdx.x >> 6);
    int lane = threadIdx.x & 63;
    if (node >= n) return;
    int grp = lane >> 5;                 // 0..1
    unsigned cols = (lane & 31) * 8;     // 0..248

    float acc[8] = {};
    int e0 = row_ptr[node], e1 = row_ptr[node + 1];

    for (int e = e0; e < e1; e += 8) {
        float nv[4]; half8 hv[4];
#pragma unroll
        for (int u = 0; u < 4; ++u) {
            int er = e + u * 2 + grp;
            int eg = min(er, e1 - 1);
            float2 c = csr[eg];
            hv[u] = *(const half8*)(H + (unsigned)__float_as_int(c.x) * 256 + cols);
            nv[u] = (er < e1) ? c.y : 0.f;
        }
#pragma unroll
        for (int u = 0; u < 4; ++u)
#pragma unroll
            for (int j = 0; j < 8; ++j)
                acc[j] += nv[u] * (float)hv[u][j];
    }

#pragma unroll
    for (int j = 0; j < 8; ++j)
        acc[j] += __shfl_down(acc[j], 32);

    float v = 0.f;
    if (lane < 32) {
        float di = dinv[node];
        float sc = di * di;
        half8 hs = *(const half8*)(H + (unsigned)node * 256 + cols);
        float4 bv0 = *(const float4*)(b4 + cols);
        float4 bv1 = *(const float4*)(b4 + cols + 4);
        float4 wv0 = *(const float4*)(Wf + cols);
        float4 wv1 = *(const float4*)(Wf + cols + 4);
        float bb[8] = {bv0.x, bv0.y, bv0.z, bv0.w, bv1.x, bv1.y, bv1.z, bv1.w};
        float ww[8] = {wv0.x, wv0.y, wv0.z, wv0.w, wv1.x, wv1.y, wv1.z, wv1.w};
#pragma unroll
        for (int j = 0; j < 8; ++j)
            v += fmaxf(acc[j] + sc * (float)hs[j] + bb[j], 0.f) * ww[j];
    }
    v += __shfl_down(v, 16);
    v += __shfl_down(v, 8);
    v += __shfl_down(v, 4);
    v += __shfl_down(v, 2);
    v += __shfl_down(v, 1);
    if (lane == 0) out[node] = v + bf[0];
}

// ---------------------------------------------------------------------------

extern "C" void kernel_launch(void* const* d_in, const int* in_sizes, int n_in,
                              void* d_out, int out_size, void* d_ws, size_t ws_size,
                              hipStream_t stream) {
    const float* x    = (const float*)d_in[0];
    const int*   eidx = (const int*)d_in[1];
    const float* eatt = (const float*)d_in[2];
    const float* W1 = (const float*)d_in[3];
    const float* b1 = (const float*)d_in[4];
    const float* W2 = (const float*)d_in[5];
    const float* b2 = (const float*)d_in[6];
    const float* W3 = (const float*)d_in[7];
    const float* b3 = (const float*)d_in[8];
    const float* W4 = (const float*)d_in[9];
    const float* b4 = (const float*)d_in[10];
    const float* Wf = (const float*)d_in[11];
    const float* bf = (const float*)d_in[12];

    const int NN = in_sizes[0] / 128;   // 50000
    const int NE = in_sizes[2];         // 800000
    const int* src = eidx;              // edge_index[0]
    const int* dst = eidx + NE;         // edge_index[1]

    // workspace layout (u64 array first for 8B alignment)
    const int Na = (NN + 64) & ~63;
    unsigned long long* packed = (unsigned long long*)d_ws;   // N u64
    float* dinv    = (float*)(packed + Na);     // N floats
    int*   row_ptr = (int*)(dinv + Na);         // N+1 ints
    int*   bsum    = row_ptr + Na;              // 64 ints
    _Float16* wf16 = (_Float16*)(bsum + 64);    // 114688 halves (W1..W4 fp16)
    int*   slot    = (int*)(wf16 + NW);         // E ints
    float2* csr    = (float2*)(slot + ((NE + 1) & ~1));   // E float2
    _Float16* bufA = (_Float16*)(csr + NE);     // N*256 halves
    _Float16* bufB = bufA + (size_t)NN * 256;   // N*256 halves

    const _Float16* W1h = wf16;
    const _Float16* W2h = wf16 + 8192;
    const _Float16* W3h = wf16 + 16384;
    const _Float16* W4h = wf16 + 49152;

    const int nscan = (NN + SCAN_CHUNK - 1) / SCAN_CHUNK;   // 25

    // --- fused preprocessing (5 launches) ---
    k_cvtw_init<<<(NW + NN + 255) / 256, 256, 0, stream>>>(W1, W2, W3, W4, wf16, packed, NN);
    k_count_slot<<<(NE + 255) / 256, 256, 0, stream>>>(dst, eatt, packed, slot, NE);
    k_dinv_scan<<<nscan, 256, 0, stream>>>(packed, dinv, row_ptr, bsum, NN);
    k_scan_add<<<nscan, 256, 0, stream>>>(row_ptr, bsum, NN, NE, nscan);
    k_fill<<<(NE + 255) / 256, 256, 0, stream>>>(src, dst, eatt, dinv, row_ptr, slot, csr, NE);

    int gw = (NN + 3) / 4;               // one wave per node, 4 waves per block
    int gx = (NN + 127) / 128;           // 391 row tiles
    int gx8 = ((gx + 7) & ~7);           // 392
    int gxcd = gx8 * 2;                  // XCD4 1-D grid (N=256, BN=128)

    // --- L1 (128->64), aggregate AFTER: H1 = x@W1; h1 = relu(gather(H1)+b1)
    gemm_mfma<false, float, 64, false><<<dim3(gx, 1), 256, 0, stream>>>(x, W1h, nullptr, bufB, NN, 128, 64);
    k_gather2<64, true><<<gw, 256, 0, stream>>>(row_ptr, csr, bufB, dinv, b1, bufA, NN);

    // --- L2 (64->128), aggregate BEFORE: g2 = gather(h1); h2 = relu(g2@W2+b2)
    k_gather2<64, false><<<gw, 256, 0, stream>>>(row_ptr, csr, bufA, dinv, nullptr, bufB, NN);
    gemm_mfma<true, _Float16, 128, false><<<dim3(gx, 1), 256, 0, stream>>>(bufB, W2h, b2, bufA, NN, 64, 128);

    // --- L3 (128->256), aggregate BEFORE: g3 = gather(h2); h3 = relu(g3@W3+b3)
    k_g128_h8<<<gw, 256, 0, stream>>>(row_ptr, csr, bufA, dinv, bufB, NN);
    gemm_mfma<true, _Float16, 128, true><<<dim3(gxcd, 1), 256, 0, stream>>>(bufB, W3h, b3, bufA, NN, 128, 256);

    // --- L4 (256->256) aggregate AFTER + fused final dot
    gemm_mfma<false, _Float16, 128, true><<<dim3(gxcd, 1), 256, 0, stream>>>(bufA, W4h, nullptr, bufB, NN, 256, 256);
    k_gfinal_h8<<<gw, 256, 0, stream>>>(row_ptr, csr, bufB, dinv, b4, Wf, bf,
                                        (float*)d_out, NN);
}

// Round 16
// 270.423 us; speedup vs baseline: 1.1069x; 1.1069x over previous
//
#include <hip/hip_runtime.h>
#include <math.h>

// ---------------------------------------------------------------------------
// EdgeCorrGNN: 4x GCNConv(+relu) + Linear(256,1).
// R16: R14 base (BN=64 GEMM — 128-tile closed as a loss). fo=64 gathers
// move to half8 16B/lane loads (the mechanism that won on fo=128/256).
// ---------------------------------------------------------------------------

typedef _Float16 half8 __attribute__((ext_vector_type(8)));
typedef _Float16 half4_t __attribute__((ext_vector_type(4)));
typedef float f32x4 __attribute__((ext_vector_type(4)));

#define SCAN_CHUNK 2048           // nodes per scan block (256 thr x 8)
#define DEG_SCALE 67108864.0f     // 2^26 fixed-point scale for weighted degree
#define DEG_MASK ((1ULL << 42) - 1)
#define NW 114688                 // total W1..W4 elements

// fused: convert W1..W4 to fp16 AND init packed degree array.
__global__ __launch_bounds__(256) void k_cvtw_init(const float* __restrict__ W1,
                                                   const float* __restrict__ W2,
                                                   const float* __restrict__ W3,
                                                   const float* __restrict__ W4,
                                                   _Float16* __restrict__ out,
                                                   unsigned long long* __restrict__ packed,
                                                   int n) {
    int i = blockIdx.x * 256 + threadIdx.x;
    if (i < NW) {
        const float* src; int off;
        if (i < 8192)       { src = W1; off = 0; }
        else if (i < 16384) { src = W2; off = 8192; }
        else if (i < 49152) { src = W3; off = 16384; }
        else                { src = W4; off = 49152; }
        out[i] = (_Float16)src[i - off];
    } else {
        int j = i - NW;
        if (j < n) packed[j] = (1ULL << 26);   // deg=1.0 (self-loop), cnt=0
    }
}

// one u64 atomic per edge; returned old count = slot within the dst row.
__global__ __launch_bounds__(256) void k_count_slot(const int* __restrict__ dst,
                                                    const float* __restrict__ w,
                                                    unsigned long long* __restrict__ packed,
                                                    int* __restrict__ slot, int e) {
    int i = blockIdx.x * 256 + threadIdx.x;
    if (i < e) {
        unsigned long long wf = (unsigned long long)(w[i] * DEG_SCALE + 0.5f);
        unsigned long long old = atomicAdd(&packed[dst[i]], (1ULL << 42) | wf);
        slot[i] = (int)(old >> 42);
    }
}

// fused: unpack packed -> dinv + per-chunk local exclusive scan of counts.
__global__ __launch_bounds__(256) void k_dinv_scan(const unsigned long long* __restrict__ packed,
                                                   float* __restrict__ dinv,
                                                   int* __restrict__ row_ptr,
                                                   int* __restrict__ blocksum, int n) {
    __shared__ int sp[256];
    int tid = threadIdx.x;
    int base = blockIdx.x * SCAN_CHUNK + tid * 8;
    int c[8] = {0, 0, 0, 0, 0, 0, 0, 0};
    if (base < n) {
#pragma unroll
        for (int j = 0; j < 8; ++j) {
            unsigned long long p = packed[base + j];
            float d = (float)((double)(p & DEG_MASK) * (1.0 / 67108864.0));
            dinv[base + j] = d > 0.0f ? rsqrtf(d) : 0.0f;
            c[j] = (int)(p >> 42);
        }
    }
    int s = c[0] + c[1] + c[2] + c[3] + c[4] + c[5] + c[6] + c[7];
    sp[tid] = s;
    __syncthreads();
    for (int d = 1; d < 256; d <<= 1) {
        int t = (tid >= d) ? sp[tid - d] : 0;
        __syncthreads();
        sp[tid] += t;
        __syncthreads();
    }
    int off = (tid == 0) ? 0 : sp[tid - 1];
    if (base < n) {
        int o[8];
        int run = off;
#pragma unroll
        for (int j = 0; j < 8; ++j) { o[j] = run; run += c[j]; }
        *(int4*)(row_ptr + base)     = make_int4(o[0], o[1], o[2], o[3]);
        *(int4*)(row_ptr + base + 4) = make_int4(o[4], o[5], o[6], o[7]);
    }
    if (tid == 255) blocksum[blockIdx.x] = sp[255];
}

// fused: wave 0 prefix-scans the (<=64) block sums; all blocks add offset.
__global__ __launch_bounds__(256) void k_scan_add(int* __restrict__ row_ptr,
                                                  const int* __restrict__ blocksum,
                                                  int n, int total, int nb) {
    __shared__ int bo[64];
    int tid = threadIdx.x;
    if (tid < 64) {
        int c = (tid < nb) ? blocksum[tid] : 0;
        int v = c;
        for (int d = 1; d < 64; d <<= 1) {
            int t = __shfl_up(v, d);
            if (tid >= d) v += t;
        }
        bo[tid] = v - c;
    }
    __syncthreads();
    int base = blockIdx.x * SCAN_CHUNK + tid * 8;
    if (base < n) {
        int off = bo[blockIdx.x];
        int4 a = *(const int4*)(row_ptr + base);
        int4 b = *(const int4*)(row_ptr + base + 4);
        a.x += off; a.y += off; a.z += off; a.w += off;
        b.x += off; b.y += off; b.z += off; b.w += off;
        *(int4*)(row_ptr + base)     = a;
        *(int4*)(row_ptr + base + 4) = b;
    }
    if (blockIdx.x == 0 && tid == 0) row_ptr[n] = total;
}

// csr[row_ptr[dst] + slot] = (src, norm) -- pure scatter, no atomics.
__global__ __launch_bounds__(256) void k_fill(const int* __restrict__ src,
                                              const int* __restrict__ dst,
                                              const float* __restrict__ w,
                                              const float* __restrict__ dinv,
                                              const int* __restrict__ row_ptr,
                                              const int* __restrict__ slot,
                                              float2* __restrict__ csr, int e) {
    int i = blockIdx.x * 256 + threadIdx.x;
    if (i < e) {
        int d = dst[i], s = src[i];
        float nv = dinv[s] * w[i] * dinv[d];
        csr[row_ptr[d] + slot[i]] = make_float2(__int_as_float(s), nv);
    }
}

// ---------------------------------------------------------------------------
// fp16-MFMA GEMM (R14): BM=128, BN=64, BK=64; 4 waves x (32x64).
// XCD4: bid -> (xcd=bid&7, cb=(bid>>3)&3, rb=xcd+8*(bid>>5)).
// ---------------------------------------------------------------------------
template <bool RELU, typename TA, bool XCD4>
__global__ __launch_bounds__(256) void gemm_mfma(const TA* __restrict__ A,
                                                 const _Float16* __restrict__ B,
                                                 const float* __restrict__ bias,
                                                 _Float16* __restrict__ C,
                                                 int M, int K, int N) {
    constexpr int PK = 72;
    __shared__ _Float16 Asl[128 * PK];
    __shared__ _Float16 Bsl[64 * PK];

    int tid = threadIdx.x;
    int w = tid >> 6, l = tid & 63;
    int row0, col0;
    if constexpr (XCD4) {
        int bid = blockIdx.x;
        int xcd = bid & 7;
        int cb = (bid >> 3) & 3;
        int rb = xcd + 8 * (bid >> 5);
        row0 = rb * 128;
        col0 = cb * 64;
    } else {
        row0 = blockIdx.x * 128;
        col0 = blockIdx.y * 64;
    }
    int wr = w * 32;
    int lr = l & 15, lg = l >> 4;

    int srow = tid >> 1;
    int skh = (tid & 1) * 32;
    int bk = tid >> 4;
    int bn = (tid & 15) * 4;

    f32x4 acc[2][4] = {};

    for (int k0 = 0; k0 < K; k0 += 64) {
        const TA* ap = A + (size_t)(row0 + srow) * K + k0 + skh;
        bool aok = (row0 + srow) < M;
#pragma unroll
        for (int i = 0; i < 4; ++i) {
            half8 h;
            if constexpr (sizeof(TA) == 4) {
                float4 v0 = aok ? *(const float4*)((const float*)ap + i * 8 + 0)
                                : make_float4(0.f, 0.f, 0.f, 0.f);
                float4 v1 = aok ? *(const float4*)((const float*)ap + i * 8 + 4)
                                : make_float4(0.f, 0.f, 0.f, 0.f);
                h[0] = (_Float16)v0.x; h[1] = (_Float16)v0.y;
                h[2] = (_Float16)v0.z; h[3] = (_Float16)v0.w;
                h[4] = (_Float16)v1.x; h[5] = (_Float16)v1.y;
                h[6] = (_Float16)v1.z; h[7] = (_Float16)v1.w;
            } else {
                h = aok ? *(const half8*)((const _Float16*)ap + i * 8)
                        : half8{0, 0, 0, 0, 0, 0, 0, 0};
            }
            *(half8*)&Asl[srow * PK + skh + i * 8] = h;
        }
#pragma unroll
        for (int r = 0; r < 4; ++r) {
            int kk = bk + r * 16;
            half4_t wv = *(const half4_t*)(B + (size_t)(k0 + kk) * N + col0 + bn);
            Bsl[(bn + 0) * PK + kk] = wv[0];
            Bsl[(bn + 1) * PK + kk] = wv[1];
            Bsl[(bn + 2) * PK + kk] = wv[2];
            Bsl[(bn + 3) * PK + kk] = wv[3];
        }
        __syncthreads();

#pragma unroll
        for (int kr = 0; kr < 2; ++kr) {
            half8 af[2], bf[4];
#pragma unroll
            for (int m = 0; m < 2; ++m)
                af[m] = *(half8*)&Asl[(wr + m * 16 + lr) * PK + kr * 32 + lg * 8];
#pragma unroll
            for (int n = 0; n < 4; ++n)
                bf[n] = *(half8*)&Bsl[(n * 16 + lr) * PK + kr * 32 + lg * 8];
#pragma unroll
            for (int m = 0; m < 2; ++m)
#pragma unroll
                for (int n = 0; n < 4; ++n)
                    acc[m][n] = __builtin_amdgcn_mfma_f32_16x16x32_f16(
                        af[m], bf[n], acc[m][n], 0, 0, 0);
        }
        __syncthreads();
    }

#pragma unroll
    for (int m = 0; m < 2; ++m) {
#pragma unroll
        for (int r = 0; r < 4; ++r) {
            int row = row0 + wr + m * 16 + lg * 4 + r;
            if (row >= M) continue;
#pragma unroll
            for (int n = 0; n < 4; ++n) {
                int col = col0 + n * 16 + lr;
                float v = acc[m][n][r];
                if (RELU) v = fmaxf(v + bias[col], 0.f);
                C[(size_t)row * N + col] = (_Float16)v;
            }
        }
    }
}

// ---------------------------------------------------------------------------
// half8 gather fo=64: one wave per node; 8 lanes x 16B cover the 128B row;
// 8 edge groups, unroll 4 (32 edge slots/iter, 64B/lane in flight).
// ---------------------------------------------------------------------------
template <bool BIASRELU>
__global__ __launch_bounds__(256) void k_g64_h8(const int* __restrict__ row_ptr,
                                                const float2* __restrict__ csr,
                                                const _Float16* __restrict__ H,
                                                const float* __restrict__ dinv,
                                                const float* __restrict__ b,
                                                _Float16* __restrict__ O, int n) {
    int node = blockIdx.x * 4 + (threadIdx.x >> 6);
    int lane = threadIdx.x & 63;
    if (node >= n) return;
    int grp = lane >> 3;                 // 0..7 edge subgroup
    unsigned cols = (lane & 7) * 8;      // 0..56

    float acc[8] = {};
    int e0 = row_ptr[node], e1 = row_ptr[node + 1];

    for (int e = e0; e < e1; e += 32) {
        float nv[4]; half8 hv[4];
#pragma unroll
        for (int u = 0; u < 4; ++u) {
            int er = e + u * 8 + grp;
            int eg = min(er, e1 - 1);
            float2 c = csr[eg];
            hv[u] = *(const half8*)(H + (unsigned)__float_as_int(c.x) * 64 + cols);
            nv[u] = (er < e1) ? c.y : 0.f;
        }
#pragma unroll
        for (int u = 0; u < 4; ++u)
#pragma unroll
            for (int j = 0; j < 8; ++j)
                acc[j] += nv[u] * (float)hv[u][j];
    }

#pragma unroll
    for (int j = 0; j < 8; ++j) {
        acc[j] += __shfl_down(acc[j], 8);
        acc[j] += __shfl_down(acc[j], 16);
        acc[j] += __shfl_down(acc[j], 32);
    }

    if (lane < 8) {
        float di = dinv[node];
        float sc = di * di;
        half8 hs = *(const half8*)(H + (unsigned)node * 64 + cols);
        half8 o;
        if (BIASRELU) {
            float4 bv0 = *(const float4*)(b + cols);
            float4 bv1 = *(const float4*)(b + cols + 4);
            float bb[8] = {bv0.x, bv0.y, bv0.z, bv0.w, bv1.x, bv1.y, bv1.z, bv1.w};
#pragma unroll
            for (int j = 0; j < 8; ++j)
                o[j] = (_Float16)fmaxf(acc[j] + sc * (float)hs[j] + bb[j], 0.f);
        } else {
#pragma unroll
            for (int j = 0; j < 8; ++j)
                o[j] = (_Float16)(acc[j] + sc * (float)hs[j]);
        }
        *(half8*)(O + (unsigned)node * 64 + cols) = o;
    }
}

// ---------------------------------------------------------------------------
// half8 gather fo=128: one wave per node; 16 lanes x 16B cover the 256B row;
// 4 edge groups, unroll 4.
// ---------------------------------------------------------------------------
__global__ __launch_bounds__(256) void k_g128_h8(const int* __restrict__ row_ptr,
                                                 const float2* __restrict__ csr,
                                                 const _Float16* __restrict__ H,
                                                 const float* __restrict__ dinv,
                                                 _Float16* __restrict__ O, int n) {
    int node = blockIdx.x * 4 + (threadIdx.x >> 6);
    int lane = threadIdx.x & 63;
    if (node >= n) return;
    int grp = lane >> 4;                 // 0..3
    unsigned cols = (lane & 15) * 8;     // 0..120

    float acc[8] = {};
    int e0 = row_ptr[node], e1 = row_ptr[node + 1];

    for (int e = e0; e < e1; e += 16) {
        float nv[4]; half8 hv[4];
#pragma unroll
        for (int u = 0; u < 4; ++u) {
            int er = e + u * 4 + grp;
            int eg = min(er, e1 - 1);
            float2 c = csr[eg];
            hv[u] = *(const half8*)(H + (unsigned)__float_as_int(c.x) * 128 + cols);
            nv[u] = (er < e1) ? c.y : 0.f;
        }
#pragma unroll
        for (int u = 0; u < 4; ++u)
#pragma unroll
            for (int j = 0; j < 8; ++j)
                acc[j] += nv[u] * (float)hv[u][j];
    }

#pragma unroll
    for (int j = 0; j < 8; ++j) {
        acc[j] += __shfl_down(acc[j], 16);
        acc[j] += __shfl_down(acc[j], 32);
    }

    if (lane < 16) {
        float di = dinv[node];
        float sc = di * di;
        half8 hs = *(const half8*)(H + (unsigned)node * 128 + cols);
        half8 o;
#pragma unroll
        for (int j = 0; j < 8; ++j)
            o[j] = (_Float16)(acc[j] + sc * (float)hs[j]);
        *(half8*)(O + (unsigned)node * 128 + cols) = o;
    }
}

// ---------------------------------------------------------------------------
// half8 fused final gather (fo=256) + bias + relu + Linear(256,1).
// One wave per node; 32 lanes x 16B cover the 512B row; 2 edge groups,
// unroll 4.
// ---------------------------------------------------------------------------
__global__ __launch_bounds__(256) void k_gfinal_h8(const int* __restrict__ row_ptr,
                                                   const float2* __restrict__ csr,
                                                   const _Float16* __restrict__ H,
                                                   const float* __restrict__ dinv,
                                                   const float* __restrict__ b4,
                                                   const float* __restrict__ Wf,
                                                   const float* __restrict__ bf,
                                                   float* __restrict__ out, int n) {
    int node = blockIdx.x * 4 + (threadIdx.x >> 6);
    int lane = threadIdx.x & 63;
    if (node >= n) return;
    int grp = lane >> 5;                 // 0..1
    unsigned cols = (lane & 31) * 8;     // 0..248

    float acc[8] = {};
    int e0 = row_ptr[node], e1 = row_ptr[node + 1];

    for (int e = e0; e < e1; e += 8) {
        float nv[4]; half8 hv[4];
#pragma unroll
        for (int u = 0; u < 4; ++u) {
            int er = e + u * 2 + grp;
            int eg = min(er, e1 - 1);
            float2 c = csr[eg];
            hv[u] = *(const half8*)(H + (unsigned)__float_as_int(c.x) * 256 + cols);
            nv[u] = (er < e1) ? c.y : 0.f;
        }
#pragma unroll
        for (int u = 0; u < 4; ++u)
#pragma unroll
            for (int j = 0; j < 8; ++j)
                acc[j] += nv[u] * (float)hv[u][j];
    }

#pragma unroll
    for (int j = 0; j < 8; ++j)
        acc[j] += __shfl_down(acc[j], 32);

    float v = 0.f;
    if (lane < 32) {
        float di = dinv[node];
        float sc = di * di;
        half8 hs = *(const half8*)(H + (unsigned)node * 256 + cols);
        float4 bv0 = *(const float4*)(b4 + cols);
        float4 bv1 = *(const float4*)(b4 + cols + 4);
        float4 wv0 = *(const float4*)(Wf + cols);
        float4 wv1 = *(const float4*)(Wf + cols + 4);
        float bb[8] = {bv0.x, bv0.y, bv0.z, bv0.w, bv1.x, bv1.y, bv1.z, bv1.w};
        float ww[8] = {wv0.x, wv0.y, wv0.z, wv0.w, wv1.x, wv1.y, wv1.z, wv1.w};
#pragma unroll
        for (int j = 0; j < 8; ++j)
            v += fmaxf(acc[j] + sc * (float)hs[j] + bb[j], 0.f) * ww[j];
    }
    v += __shfl_down(v, 16);
    v += __shfl_down(v, 8);
    v += __shfl_down(v, 4);
    v += __shfl_down(v, 2);
    v += __shfl_down(v, 1);
    if (lane == 0) out[node] = v + bf[0];
}

// ---------------------------------------------------------------------------

extern "C" void kernel_launch(void* const* d_in, const int* in_sizes, int n_in,
                              void* d_out, int out_size, void* d_ws, size_t ws_size,
                              hipStream_t stream) {
    const float* x    = (const float*)d_in[0];
    const int*   eidx = (const int*)d_in[1];
    const float* eatt = (const float*)d_in[2];
    const float* W1 = (const float*)d_in[3];
    const float* b1 = (const float*)d_in[4];
    const float* W2 = (const float*)d_in[5];
    const float* b2 = (const float*)d_in[6];
    const float* W3 = (const float*)d_in[7];
    const float* b3 = (const float*)d_in[8];
    const float* W4 = (const float*)d_in[9];
    const float* b4 = (const float*)d_in[10];
    const float* Wf = (const float*)d_in[11];
    const float* bf = (const float*)d_in[12];

    const int NN = in_sizes[0] / 128;   // 50000
    const int NE = in_sizes[2];         // 800000
    const int* src = eidx;              // edge_index[0]
    const int* dst = eidx + NE;         // edge_index[1]

    // workspace layout (u64 array first for 8B alignment)
    const int Na = (NN + 64) & ~63;
    unsigned long long* packed = (unsigned long long*)d_ws;   // N u64
    float* dinv    = (float*)(packed + Na);     // N floats
    int*   row_ptr = (int*)(dinv + Na);         // N+1 ints
    int*   bsum    = row_ptr + Na;              // 64 ints
    _Float16* wf16 = (_Float16*)(bsum + 64);    // 114688 halves (W1..W4 fp16)
    int*   slot    = (int*)(wf16 + NW);         // E ints
    float2* csr    = (float2*)(slot + ((NE + 1) & ~1));   // E float2
    _Float16* bufA = (_Float16*)(csr + NE);     // N*256 halves
    _Float16* bufB = bufA + (size_t)NN * 256;   // N*256 halves

    const _Float16* W1h = wf16;
    const _Float16* W2h = wf16 + 8192;
    const _Float16* W3h = wf16 + 16384;
    const _Float16* W4h = wf16 + 49152;

    const int nscan = (NN + SCAN_CHUNK - 1) / SCAN_CHUNK;   // 25

    // --- fused preprocessing (5 launches) ---
    k_cvtw_init<<<(NW + NN + 255) / 256, 256, 0, stream>>>(W1, W2, W3, W4, wf16, packed, NN);
    k_count_slot<<<(NE + 255) / 256, 256, 0, stream>>>(dst, eatt, packed, slot, NE);
    k_dinv_scan<<<nscan, 256, 0, stream>>>(packed, dinv, row_ptr, bsum, NN);
    k_scan_add<<<nscan, 256, 0, stream>>>(row_ptr, bsum, NN, NE, nscan);
    k_fill<<<(NE + 255) / 256, 256, 0, stream>>>(src, dst, eatt, dinv, row_ptr, slot, csr, NE);

    int gw = (NN + 3) / 4;               // one wave per node, 4 waves per block
    int gx = (NN + 127) / 128;           // 391 row tiles
    int gx8 = ((gx + 7) & ~7);
    int gxcd = gx8 * 4;                  // XCD4 1-D grid (N=256)

    // --- L1 (128->64), aggregate AFTER: H1 = x@W1; h1 = relu(gather(H1)+b1)
    gemm_mfma<false, float, false><<<dim3(gx, 1), 256, 0, stream>>>(x, W1h, nullptr, bufB, NN, 128, 64);
    k_g64_h8<true><<<gw, 256, 0, stream>>>(row_ptr, csr, bufB, dinv, b1, bufA, NN);

    // --- L2 (64->128), aggregate BEFORE: g2 = gather(h1); h2 = relu(g2@W2+b2)
    k_g64_h8<false><<<gw, 256, 0, stream>>>(row_ptr, csr, bufA, dinv, nullptr, bufB, NN);
    gemm_mfma<true, _Float16, false><<<dim3(gx, 2), 256, 0, stream>>>(bufB, W2h, b2, bufA, NN, 64, 128);

    // --- L3 (128->256), aggregate BEFORE: g3 = gather(h2); h3 = relu(g3@W3+b3)
    k_g128_h8<<<gw, 256, 0, stream>>>(row_ptr, csr, bufA, dinv, bufB, NN);
    gemm_mfma<true, _Float16, true><<<dim3(gxcd, 1), 256, 0, stream>>>(bufB, W3h, b3, bufA, NN, 128, 256);

    // --- L4 (256->256) aggregate AFTER + fused final dot
    gemm_mfma<false, _Float16, true><<<dim3(gxcd, 1), 256, 0, stream>>>(bufA, W4h, nullptr, bufB, NN, 256, 256);
    k_gfinal_h8<<<gw, 256, 0, stream>>>(row_ptr, csr, bufB, dinv, b4, Wf, bf,
                                        (float*)d_out, NN);
}

// Round 17
// 257.850 us; speedup vs baseline: 1.1609x; 1.0488x over previous
//
#include <hip/hip_runtime.h>
#include <math.h>

// ---------------------------------------------------------------------------
// EdgeCorrGNN: 4x GCNConv(+relu) + Linear(256,1).
// R17: R16 base + heterogeneous merge: L1 GEMM (MFMA-bound, independent of
// graph preproc) runs in the same kernel as count_slot (atomic-bound, CUs
// idle) -- blocks [0,gx) = GEMM tiles, [gx,..) = edge atomics.
// ---------------------------------------------------------------------------

typedef _Float16 half8 __attribute__((ext_vector_type(8)));
typedef _Float16 half4_t __attribute__((ext_vector_type(4)));
typedef float f32x4 __attribute__((ext_vector_type(4)));

#define SCAN_CHUNK 2048           // nodes per scan block (256 thr x 8)
#define DEG_SCALE 67108864.0f     // 2^26 fixed-point scale for weighted degree
#define DEG_MASK ((1ULL << 42) - 1)
#define NW 114688                 // total W1..W4 elements

// fused: convert W1..W4 to fp16 AND init packed degree array.
__global__ __launch_bounds__(256) void k_cvtw_init(const float* __restrict__ W1,
                                                   const float* __restrict__ W2,
                                                   const float* __restrict__ W3,
                                                   const float* __restrict__ W4,
                                                   _Float16* __restrict__ out,
                                                   unsigned long long* __restrict__ packed,
                                                   int n) {
    int i = blockIdx.x * 256 + threadIdx.x;
    if (i < NW) {
        const float* src; int off;
        if (i < 8192)       { src = W1; off = 0; }
        else if (i < 16384) { src = W2; off = 8192; }
        else if (i < 49152) { src = W3; off = 16384; }
        else                { src = W4; off = 49152; }
        out[i] = (_Float16)src[i - off];
    } else {
        int j = i - NW;
        if (j < n) packed[j] = (1ULL << 26);   // deg=1.0 (self-loop), cnt=0
    }
}

// ---------------------------------------------------------------------------
// GEMM tile body (BM=128, BN=64, BK=64; 4 waves x 32x64). Device function so
// it can run both standalone and inside the heterogeneous merge kernel.
// ---------------------------------------------------------------------------
template <bool RELU, typename TA>
__device__ __forceinline__ void gemm_tile(const TA* __restrict__ A,
                                          const _Float16* __restrict__ B,
                                          const float* __restrict__ bias,
                                          _Float16* __restrict__ C,
                                          int M, int K, int N,
                                          int row0, int col0) {
    constexpr int PK = 72;
    __shared__ _Float16 Asl[128 * PK];
    __shared__ _Float16 Bsl[64 * PK];

    int tid = threadIdx.x;
    int w = tid >> 6, l = tid & 63;
    int wr = w * 32;
    int lr = l & 15, lg = l >> 4;

    int srow = tid >> 1;
    int skh = (tid & 1) * 32;
    int bk = tid >> 4;
    int bn = (tid & 15) * 4;

    f32x4 acc[2][4] = {};

    for (int k0 = 0; k0 < K; k0 += 64) {
        const TA* ap = A + (size_t)(row0 + srow) * K + k0 + skh;
        bool aok = (row0 + srow) < M;
#pragma unroll
        for (int i = 0; i < 4; ++i) {
            half8 h;
            if constexpr (sizeof(TA) == 4) {
                float4 v0 = aok ? *(const float4*)((const float*)ap + i * 8 + 0)
                                : make_float4(0.f, 0.f, 0.f, 0.f);
                float4 v1 = aok ? *(const float4*)((const float*)ap + i * 8 + 4)
                                : make_float4(0.f, 0.f, 0.f, 0.f);
                h[0] = (_Float16)v0.x; h[1] = (_Float16)v0.y;
                h[2] = (_Float16)v0.z; h[3] = (_Float16)v0.w;
                h[4] = (_Float16)v1.x; h[5] = (_Float16)v1.y;
                h[6] = (_Float16)v1.z; h[7] = (_Float16)v1.w;
            } else {
                h = aok ? *(const half8*)((const _Float16*)ap + i * 8)
                        : half8{0, 0, 0, 0, 0, 0, 0, 0};
            }
            *(half8*)&Asl[srow * PK + skh + i * 8] = h;
        }
#pragma unroll
        for (int r = 0; r < 4; ++r) {
            int kk = bk + r * 16;
            half4_t wv = *(const half4_t*)(B + (size_t)(k0 + kk) * N + col0 + bn);
            Bsl[(bn + 0) * PK + kk] = wv[0];
            Bsl[(bn + 1) * PK + kk] = wv[1];
            Bsl[(bn + 2) * PK + kk] = wv[2];
            Bsl[(bn + 3) * PK + kk] = wv[3];
        }
        __syncthreads();

#pragma unroll
        for (int kr = 0; kr < 2; ++kr) {
            half8 af[2], bf[4];
#pragma unroll
            for (int m = 0; m < 2; ++m)
                af[m] = *(half8*)&Asl[(wr + m * 16 + lr) * PK + kr * 32 + lg * 8];
#pragma unroll
            for (int n = 0; n < 4; ++n)
                bf[n] = *(half8*)&Bsl[(n * 16 + lr) * PK + kr * 32 + lg * 8];
#pragma unroll
            for (int m = 0; m < 2; ++m)
#pragma unroll
                for (int n = 0; n < 4; ++n)
                    acc[m][n] = __builtin_amdgcn_mfma_f32_16x16x32_f16(
                        af[m], bf[n], acc[m][n], 0, 0, 0);
        }
        __syncthreads();
    }

#pragma unroll
    for (int m = 0; m < 2; ++m) {
#pragma unroll
        for (int r = 0; r < 4; ++r) {
            int row = row0 + wr + m * 16 + lg * 4 + r;
            if (row >= M) continue;
#pragma unroll
            for (int n = 0; n < 4; ++n) {
                int col = col0 + n * 16 + lr;
                float v = acc[m][n][r];
                if (RELU) v = fmaxf(v + bias[col], 0.f);
                C[(size_t)row * N + col] = (_Float16)v;
            }
        }
    }
}

// heterogeneous merge: blocks [0,gx) compute L1 GEMM (x@W1 -> H1);
// blocks [gx,..) run the per-edge u64 atomic count+slot.
__global__ __launch_bounds__(256) void k_count_gemm1(const float* __restrict__ x,
                                                     const _Float16* __restrict__ W1h,
                                                     _Float16* __restrict__ H1,
                                                     int M,
                                                     const int* __restrict__ dst,
                                                     const float* __restrict__ w,
                                                     unsigned long long* __restrict__ packed,
                                                     int* __restrict__ slot,
                                                     int e, int gx) {
    int bid = blockIdx.x;
    if (bid < gx) {
        gemm_tile<false, float>(x, W1h, nullptr, H1, M, 128, 64, bid * 128, 0);
    } else {
        int i = (bid - gx) * 256 + threadIdx.x;
        if (i < e) {
            unsigned long long wf = (unsigned long long)(w[i] * DEG_SCALE + 0.5f);
            unsigned long long old = atomicAdd(&packed[dst[i]], (1ULL << 42) | wf);
            slot[i] = (int)(old >> 42);
        }
    }
}

// standalone GEMM kernel (L2..L4). XCD4: bid -> (xcd, cb, rb) decode.
template <bool RELU, typename TA, bool XCD4>
__global__ __launch_bounds__(256) void gemm_mfma(const TA* __restrict__ A,
                                                 const _Float16* __restrict__ B,
                                                 const float* __restrict__ bias,
                                                 _Float16* __restrict__ C,
                                                 int M, int K, int N) {
    int row0, col0;
    if constexpr (XCD4) {
        int bid = blockIdx.x;
        int xcd = bid & 7;
        int cb = (bid >> 3) & 3;
        int rb = xcd + 8 * (bid >> 5);
        row0 = rb * 128;
        col0 = cb * 64;
    } else {
        row0 = blockIdx.x * 128;
        col0 = blockIdx.y * 64;
    }
    gemm_tile<RELU, TA>(A, B, bias, C, M, K, N, row0, col0);
}

// fused: unpack packed -> dinv + per-chunk local exclusive scan of counts.
__global__ __launch_bounds__(256) void k_dinv_scan(const unsigned long long* __restrict__ packed,
                                                   float* __restrict__ dinv,
                                                   int* __restrict__ row_ptr,
                                                   int* __restrict__ blocksum, int n) {
    __shared__ int sp[256];
    int tid = threadIdx.x;
    int base = blockIdx.x * SCAN_CHUNK + tid * 8;
    int c[8] = {0, 0, 0, 0, 0, 0, 0, 0};
    if (base < n) {
#pragma unroll
        for (int j = 0; j < 8; ++j) {
            unsigned long long p = packed[base + j];
            float d = (float)((double)(p & DEG_MASK) * (1.0 / 67108864.0));
            dinv[base + j] = d > 0.0f ? rsqrtf(d) : 0.0f;
            c[j] = (int)(p >> 42);
        }
    }
    int s = c[0] + c[1] + c[2] + c[3] + c[4] + c[5] + c[6] + c[7];
    sp[tid] = s;
    __syncthreads();
    for (int d = 1; d < 256; d <<= 1) {
        int t = (tid >= d) ? sp[tid - d] : 0;
        __syncthreads();
        sp[tid] += t;
        __syncthreads();
    }
    int off = (tid == 0) ? 0 : sp[tid - 1];
    if (base < n) {
        int o[8];
        int run = off;
#pragma unroll
        for (int j = 0; j < 8; ++j) { o[j] = run; run += c[j]; }
        *(int4*)(row_ptr + base)     = make_int4(o[0], o[1], o[2], o[3]);
        *(int4*)(row_ptr + base + 4) = make_int4(o[4], o[5], o[6], o[7]);
    }
    if (tid == 255) blocksum[blockIdx.x] = sp[255];
}

// fused: wave 0 prefix-scans the (<=64) block sums; all blocks add offset.
__global__ __launch_bounds__(256) void k_scan_add(int* __restrict__ row_ptr,
                                                  const int* __restrict__ blocksum,
                                                  int n, int total, int nb) {
    __shared__ int bo[64];
    int tid = threadIdx.x;
    if (tid < 64) {
        int c = (tid < nb) ? blocksum[tid] : 0;
        int v = c;
        for (int d = 1; d < 64; d <<= 1) {
            int t = __shfl_up(v, d);
            if (tid >= d) v += t;
        }
        bo[tid] = v - c;
    }
    __syncthreads();
    int base = blockIdx.x * SCAN_CHUNK + tid * 8;
    if (base < n) {
        int off = bo[blockIdx.x];
        int4 a = *(const int4*)(row_ptr + base);
        int4 b = *(const int4*)(row_ptr + base + 4);
        a.x += off; a.y += off; a.z += off; a.w += off;
        b.x += off; b.y += off; b.z += off; b.w += off;
        *(int4*)(row_ptr + base)     = a;
        *(int4*)(row_ptr + base + 4) = b;
    }
    if (blockIdx.x == 0 && tid == 0) row_ptr[n] = total;
}

// csr[row_ptr[dst] + slot] = (src, norm) -- pure scatter, no atomics.
__global__ __launch_bounds__(256) void k_fill(const int* __restrict__ src,
                                              const int* __restrict__ dst,
                                              const float* __restrict__ w,
                                              const float* __restrict__ dinv,
                                              const int* __restrict__ row_ptr,
                                              const int* __restrict__ slot,
                                              float2* __restrict__ csr, int e) {
    int i = blockIdx.x * 256 + threadIdx.x;
    if (i < e) {
        int d = dst[i], s = src[i];
        float nv = dinv[s] * w[i] * dinv[d];
        csr[row_ptr[d] + slot[i]] = make_float2(__int_as_float(s), nv);
    }
}

// ---------------------------------------------------------------------------
// half8 gather fo=64: one wave per node; 8 lanes x 16B cover the 128B row;
// 8 edge groups, unroll 4 (32 edge slots/iter).
// ---------------------------------------------------------------------------
template <bool BIASRELU>
__global__ __launch_bounds__(256) void k_g64_h8(const int* __restrict__ row_ptr,
                                                const float2* __restrict__ csr,
                                                const _Float16* __restrict__ H,
                                                const float* __restrict__ dinv,
                                                const float* __restrict__ b,
                                                _Float16* __restrict__ O, int n) {
    int node = blockIdx.x * 4 + (threadIdx.x >> 6);
    int lane = threadIdx.x & 63;
    if (node >= n) return;
    int grp = lane >> 3;                 // 0..7 edge subgroup
    unsigned cols = (lane & 7) * 8;      // 0..56

    float acc[8] = {};
    int e0 = row_ptr[node], e1 = row_ptr[node + 1];

    for (int e = e0; e < e1; e += 32) {
        float nv[4]; half8 hv[4];
#pragma unroll
        for (int u = 0; u < 4; ++u) {
            int er = e + u * 8 + grp;
            int eg = min(er, e1 - 1);
            float2 c = csr[eg];
            hv[u] = *(const half8*)(H + (unsigned)__float_as_int(c.x) * 64 + cols);
            nv[u] = (er < e1) ? c.y : 0.f;
        }
#pragma unroll
        for (int u = 0; u < 4; ++u)
#pragma unroll
            for (int j = 0; j < 8; ++j)
                acc[j] += nv[u] * (float)hv[u][j];
    }

#pragma unroll
    for (int j = 0; j < 8; ++j) {
        acc[j] += __shfl_down(acc[j], 8);
        acc[j] += __shfl_down(acc[j], 16);
        acc[j] += __shfl_down(acc[j], 32);
    }

    if (lane < 8) {
        float di = dinv[node];
        float sc = di * di;
        half8 hs = *(const half8*)(H + (unsigned)node * 64 + cols);
        half8 o;
        if (BIASRELU) {
            float4 bv0 = *(const float4*)(b + cols);
            float4 bv1 = *(const float4*)(b + cols + 4);
            float bb[8] = {bv0.x, bv0.y, bv0.z, bv0.w, bv1.x, bv1.y, bv1.z, bv1.w};
#pragma unroll
            for (int j = 0; j < 8; ++j)
                o[j] = (_Float16)fmaxf(acc[j] + sc * (float)hs[j] + bb[j], 0.f);
        } else {
#pragma unroll
            for (int j = 0; j < 8; ++j)
                o[j] = (_Float16)(acc[j] + sc * (float)hs[j]);
        }
        *(half8*)(O + (unsigned)node * 64 + cols) = o;
    }
}

// ---------------------------------------------------------------------------
// half8 gather fo=128: one wave per node; 16 lanes x 16B; 4 edge groups.
// ---------------------------------------------------------------------------
__global__ __launch_bounds__(256) void k_g128_h8(const int* __restrict__ row_ptr,
                                                 const float2* __restrict__ csr,
                                                 const _Float16* __restrict__ H,
                                                 const float* __restrict__ dinv,
                                                 _Float16* __restrict__ O, int n) {
    int node = blockIdx.x * 4 + (threadIdx.x >> 6);
    int lane = threadIdx.x & 63;
    if (node >= n) return;
    int grp = lane >> 4;                 // 0..3
    unsigned cols = (lane & 15) * 8;     // 0..120

    float acc[8] = {};
    int e0 = row_ptr[node], e1 = row_ptr[node + 1];

    for (int e = e0; e < e1; e += 16) {
        float nv[4]; half8 hv[4];
#pragma unroll
        for (int u = 0; u < 4; ++u) {
            int er = e + u * 4 + grp;
            int eg = min(er, e1 - 1);
            float2 c = csr[eg];
            hv[u] = *(const half8*)(H + (unsigned)__float_as_int(c.x) * 128 + cols);
            nv[u] = (er < e1) ? c.y : 0.f;
        }
#pragma unroll
        for (int u = 0; u < 4; ++u)
#pragma unroll
            for (int j = 0; j < 8; ++j)
                acc[j] += nv[u] * (float)hv[u][j];
    }

#pragma unroll
    for (int j = 0; j < 8; ++j) {
        acc[j] += __shfl_down(acc[j], 16);
        acc[j] += __shfl_down(acc[j], 32);
    }

    if (lane < 16) {
        float di = dinv[node];
        float sc = di * di;
        half8 hs = *(const half8*)(H + (unsigned)node * 128 + cols);
        half8 o;
#pragma unroll
        for (int j = 0; j < 8; ++j)
            o[j] = (_Float16)(acc[j] + sc * (float)hs[j]);
        *(half8*)(O + (unsigned)node * 128 + cols) = o;
    }
}

// ---------------------------------------------------------------------------
// half8 fused final gather (fo=256) + bias + relu + Linear(256,1).
// ---------------------------------------------------------------------------
__global__ __launch_bounds__(256) void k_gfinal_h8(const int* __restrict__ row_ptr,
                                                   const float2* __restrict__ csr,
                                                   const _Float16* __restrict__ H,
                                                   const float* __restrict__ dinv,
                                                   const float* __restrict__ b4,
                                                   const float* __restrict__ Wf,
                                                   const float* __restrict__ bf,
                                                   float* __restrict__ out, int n) {
    int node = blockIdx.x * 4 + (threadIdx.x >> 6);
    int lane = threadIdx.x & 63;
    if (node >= n) return;
    int grp = lane >> 5;                 // 0..1
    unsigned cols = (lane & 31) * 8;     // 0..248

    float acc[8] = {};
    int e0 = row_ptr[node], e1 = row_ptr[node + 1];

    for (int e = e0; e < e1; e += 8) {
        float nv[4]; half8 hv[4];
#pragma unroll
        for (int u = 0; u < 4; ++u) {
            int er = e + u * 2 + grp;
            int eg = min(er, e1 - 1);
            float2 c = csr[eg];
            hv[u] = *(const half8*)(H + (unsigned)__float_as_int(c.x) * 256 + cols);
            nv[u] = (er < e1) ? c.y : 0.f;
        }
#pragma unroll
        for (int u = 0; u < 4; ++u)
#pragma unroll
            for (int j = 0; j < 8; ++j)
                acc[j] += nv[u] * (float)hv[u][j];
    }

#pragma unroll
    for (int j = 0; j < 8; ++j)
        acc[j] += __shfl_down(acc[j], 32);

    float v = 0.f;
    if (lane < 32) {
        float di = dinv[node];
        float sc = di * di;
        half8 hs = *(const half8*)(H + (unsigned)node * 256 + cols);
        float4 bv0 = *(const float4*)(b4 + cols);
        float4 bv1 = *(const float4*)(b4 + cols + 4);
        float4 wv0 = *(const float4*)(Wf + cols);
        float4 wv1 = *(const float4*)(Wf + cols + 4);
        float bb[8] = {bv0.x, bv0.y, bv0.z, bv0.w, bv1.x, bv1.y, bv1.z, bv1.w};
        float ww[8] = {wv0.x, wv0.y, wv0.z, wv0.w, wv1.x, wv1.y, wv1.z, wv1.w};
#pragma unroll
        for (int j = 0; j < 8; ++j)
            v += fmaxf(acc[j] + sc * (float)hs[j] + bb[j], 0.f) * ww[j];
    }
    v += __shfl_down(v, 16);
    v += __shfl_down(v, 8);
    v += __shfl_down(v, 4);
    v += __shfl_down(v, 2);
    v += __shfl_down(v, 1);
    if (lane == 0) out[node] = v + bf[0];
}

// ---------------------------------------------------------------------------

extern "C" void kernel_launch(void* const* d_in, const int* in_sizes, int n_in,
                              void* d_out, int out_size, void* d_ws, size_t ws_size,
                              hipStream_t stream) {
    const float* x    = (const float*)d_in[0];
    const int*   eidx = (const int*)d_in[1];
    const float* eatt = (const float*)d_in[2];
    const float* W1 = (const float*)d_in[3];
    const float* b1 = (const float*)d_in[4];
    const float* W2 = (const float*)d_in[5];
    const float* b2 = (const float*)d_in[6];
    const float* W3 = (const float*)d_in[7];
    const float* b3 = (const float*)d_in[8];
    const float* W4 = (const float*)d_in[9];
    const float* b4 = (const float*)d_in[10];
    const float* Wf = (const float*)d_in[11];
    const float* bf = (const float*)d_in[12];

    const int NN = in_sizes[0] / 128;   // 50000
    const int NE = in_sizes[2];         // 800000
    const int* src = eidx;              // edge_index[0]
    const int* dst = eidx + NE;         // edge_index[1]

    // workspace layout (u64 array first for 8B alignment)
    const int Na = (NN + 64) & ~63;
    unsigned long long* packed = (unsigned long long*)d_ws;   // N u64
    float* dinv    = (float*)(packed + Na);     // N floats
    int*   row_ptr = (int*)(dinv + Na);         // N+1 ints
    int*   bsum    = row_ptr + Na;              // 64 ints
    _Float16* wf16 = (_Float16*)(bsum + 64);    // 114688 halves (W1..W4 fp16)
    int*   slot    = (int*)(wf16 + NW);         // E ints
    float2* csr    = (float2*)(slot + ((NE + 1) & ~1));   // E float2
    _Float16* bufA = (_Float16*)(csr + NE);     // N*256 halves
    _Float16* bufB = bufA + (size_t)NN * 256;   // N*256 halves

    const _Float16* W1h = wf16;
    const _Float16* W2h = wf16 + 8192;
    const _Float16* W3h = wf16 + 16384;
    const _Float16* W4h = wf16 + 49152;

    const int nscan = (NN + SCAN_CHUNK - 1) / SCAN_CHUNK;   // 25
    int gw = (NN + 3) / 4;               // one wave per node, 4 waves per block
    int gx = (NN + 127) / 128;           // 391 row tiles
    int gx8 = ((gx + 7) & ~7);
    int gxcd = gx8 * 4;                  // XCD4 1-D grid (N=256)
    int gcnt = (NE + 255) / 256;         // edge blocks

    // --- preprocessing; L1 GEMM merged with count_slot (independent work) ---
    k_cvtw_init<<<(NW + NN + 255) / 256, 256, 0, stream>>>(W1, W2, W3, W4, wf16, packed, NN);
    k_count_gemm1<<<gx + gcnt, 256, 0, stream>>>(x, W1h, bufB, NN, dst, eatt, packed, slot, NE, gx);
    k_dinv_scan<<<nscan, 256, 0, stream>>>(packed, dinv, row_ptr, bsum, NN);
    k_scan_add<<<nscan, 256, 0, stream>>>(row_ptr, bsum, NN, NE, nscan);
    k_fill<<<gcnt, 256, 0, stream>>>(src, dst, eatt, dinv, row_ptr, slot, csr, NE);

    // --- L1 aggregate: h1 = relu(gather(H1)+b1)
    k_g64_h8<true><<<gw, 256, 0, stream>>>(row_ptr, csr, bufB, dinv, b1, bufA, NN);

    // --- L2 (64->128), aggregate BEFORE: g2 = gather(h1); h2 = relu(g2@W2+b2)
    k_g64_h8<false><<<gw, 256, 0, stream>>>(row_ptr, csr, bufA, dinv, nullptr, bufB, NN);
    gemm_mfma<true, _Float16, false><<<dim3(gx, 2), 256, 0, stream>>>(bufB, W2h, b2, bufA, NN, 64, 128);

    // --- L3 (128->256), aggregate BEFORE: g3 = gather(h2); h3 = relu(g3@W3+b3)
    k_g128_h8<<<gw, 256, 0, stream>>>(row_ptr, csr, bufA, dinv, bufB, NN);
    gemm_mfma<true, _Float16, true><<<dim3(gxcd, 1), 256, 0, stream>>>(bufB, W3h, b3, bufA, NN, 128, 256);

    // --- L4 (256->256) aggregate AFTER + fused final dot
    gemm_mfma<false, _Float16, true><<<dim3(gxcd, 1), 256, 0, stream>>>(bufA, W4h, nullptr, bufB, NN, 256, 256);
    k_gfinal_h8<<<gw, 256, 0, stream>>>(row_ptr, csr, bufB, dinv, b4, Wf, bf,
                                        (float*)d_out, NN);
}